// Round 8
// baseline (289.927 us; speedup 1.0000x reference)
//
#include <hip/hip_runtime.h>
#include <hip/hip_bf16.h>
#include <stdint.h>

typedef __bf16 bf16x8 __attribute__((ext_vector_type(8)));
typedef __bf16 bf16x4 __attribute__((ext_vector_type(4)));
typedef float f32x4 __attribute__((ext_vector_type(4)));

#define B_ 2
#define LQ_ 2048
#define LK_ 2048
#define NH_ 16
#define DH_ 64
#define DM_ 1024
#define NKT_ (LK_ / 64)

#define AS1 __attribute__((address_space(1)))
#define AS3 __attribute__((address_space(3)))

__device__ __forceinline__ void gload_lds16(const void* g, void* l) {
  __builtin_amdgcn_global_load_lds((const AS1 uint32_t*)g, (AS3 uint32_t*)l, 16, 0, 0);
}

// Fused prep: blocks [0,960) convert q,k,v,Wq,Wk,Wv fp32 -> bf16 k-tiled
// T[kt][row][32] (chunk c' stores true chunk c'^(row&3)); blocks [960,9152)
// pack the mask to bits.
__global__ __launch_bounds__(256) void prep_kernel(
    const float* __restrict__ q, const float* __restrict__ k,
    const float* __restrict__ v, const float* __restrict__ wq,
    const float* __restrict__ wk, const float* __restrict__ wv,
    const int* __restrict__ mask,
    __bf16* __restrict__ Xt0, __bf16* __restrict__ Xt1, __bf16* __restrict__ Xt2,
    __bf16* __restrict__ Wt0, __bf16* __restrict__ Wt1, __bf16* __restrict__ Wt2,
    unsigned* __restrict__ maskp) {
  const int t = threadIdx.x;
  const int bidx = blockIdx.x;
  if (bidx >= 960) {
    // ---- mask pack: thread covers 4 ints; nibble OR-reduce over 8 lanes ----
    int pb = bidx - 960;
    int lane = t & 63;
    size_t gi = ((size_t)pb * 256 + t) * 4;
    int4 mv = *(const int4*)(mask + gi);
    unsigned nib = (mv.x != 0 ? 1u : 0u) | (mv.y != 0 ? 2u : 0u) |
                   (mv.z != 0 ? 4u : 0u) | (mv.w != 0 ? 8u : 0u);
    unsigned vv = nib << ((lane & 7) * 4);
    vv |= __shfl_xor(vv, 1, 64);
    vv |= __shfl_xor(vv, 2, 64);
    vv |= __shfl_xor(vv, 4, 64);
    if ((lane & 7) == 0) maskp[gi >> 5] = vv;
    return;
  }
  // ---- cvt: 16 source rows x 1024 k through LDS transpose ----
  __shared__ __align__(16) __bf16 lb[16][1032];
  const float* src; __bf16* dst; int rows, m0;
  if (bidx < 256)      { src = q;  dst = Xt0; rows = 4096; m0 = bidx * 16; }
  else if (bidx < 512) { src = k;  dst = Xt1; rows = 4096; m0 = (bidx - 256) * 16; }
  else if (bidx < 768) { src = v;  dst = Xt2; rows = 4096; m0 = (bidx - 512) * 16; }
  else if (bidx < 832) { src = wq; dst = Wt0; rows = 1024; m0 = (bidx - 768) * 16; }
  else if (bidx < 896) { src = wk; dst = Wt1; rows = 1024; m0 = (bidx - 832) * 16; }
  else                 { src = wv; dst = Wt2; rows = 1024; m0 = (bidx - 896) * 16; }
#pragma unroll
  for (int i = 0; i < 16; i++) {
    float4 f = *(const float4*)(src + (size_t)(m0 + i) * DM_ + t * 4);
    bf16x4 o;
    o[0] = (__bf16)f.x; o[1] = (__bf16)f.y; o[2] = (__bf16)f.z; o[3] = (__bf16)f.w;
    *(bf16x4*)&lb[i][t * 4] = o;
  }
  __syncthreads();
  const int wave = t >> 6, lane = t & 63;
  const int m = lane >> 2, c = lane & 3;
#pragma unroll
  for (int j = 0; j < 8; j++) {
    int kt = wave * 8 + j;
    bf16x8 val = *(const bf16x8*)&lb[m][kt * 32 + (c ^ (m & 3)) * 8];
    *(bf16x8*)(dst + ((size_t)kt * rows + m0 + m) * 32 + c * 8) = val;  // 1KB/instr
  }
}

// GEMM C = X @ W^T + bias, 128x128 tile, BK=32, double-buffered staging from
// k-tiled inputs: each global_load_lds covers one contiguous 1KB span.
// mode=blockIdx.z: 0=q(std), 1=k(std+T), 2=v(T). T out: T[bh][kti][d][64].
// mode-0 (qh) output pre-scaled by log2e/8 so attn's exp2 needs no mul.
__global__ __launch_bounds__(256) void proj_kernel(
    const __bf16* __restrict__ Xt0, const __bf16* __restrict__ Xt1,
    const __bf16* __restrict__ Xt2,
    const float* __restrict__ b0p, const float* __restrict__ b1p,
    const float* __restrict__ b2p,
    const __bf16* __restrict__ Wt0, const __bf16* __restrict__ Wt1,
    const __bf16* __restrict__ Wt2,
    __bf16* __restrict__ qh, __bf16* __restrict__ kh,
    __bf16* __restrict__ khT, __bf16* __restrict__ vhT) {
  __shared__ __align__(16) __bf16 smem[2][2][128 * 32];
  __bf16* cbuf = &smem[0][0][0];  // epilogue alias (18 KB < 32 KB)

  const int mode = blockIdx.z;
  const __bf16* Xt = mode == 0 ? Xt0 : (mode == 1 ? Xt1 : Xt2);
  const __bf16* Wt = mode == 0 ? Wt0 : (mode == 1 ? Wt1 : Wt2);
  const float* bias = mode == 0 ? b0p : (mode == 1 ? b1p : b2p);
  __bf16* ostd = mode == 0 ? qh : (mode == 1 ? kh : nullptr);
  __bf16* otr = mode == 0 ? nullptr : (mode == 1 ? khT : vhT);
  const float osc = mode == 0 ? 0.18033688f : 1.0f;  // log2(e)/8 folded into Q

  const int t = threadIdx.x;
  const int wave = t >> 6, lane = t & 63;
  const int lo16 = lane & 15, quad = lane >> 4;
  const int wm = wave >> 1, wn = wave & 1;
  const int m0 = blockIdx.x * 128, n0 = blockIdx.y * 128;

  f32x4 acc[4][4] = {};

  auto stage = [&](int kt, int sel) {
#pragma unroll
    for (int ii = 2 * wave; ii < 2 * wave + 2; ii++) {
      gload_lds16(Xt + ((size_t)kt * 4096 + m0 + ii * 16) * 32 + lane * 8,
                  &smem[sel][0][ii * 512]);
      gload_lds16(Wt + ((size_t)kt * 1024 + n0 + ii * 16) * 32 + lane * 8,
                  &smem[sel][1][ii * 512]);
    }
  };

  stage(0, 0);
  for (int kt = 0; kt < 32; kt++) {
    const int sel = kt & 1;
    __syncthreads();
    if (kt + 1 < 32) stage(kt + 1, sel ^ 1);
    bf16x8 af[4], bfr[4];
#pragma unroll
    for (int g = 0; g < 4; g++) {
      int ar = wm * 64 + g * 16 + lo16;
      af[g] = *(const bf16x8*)(&smem[sel][0][ar * 32 + (quad ^ (ar & 3)) * 8]);
      int br = wn * 64 + g * 16 + lo16;
      bfr[g] = *(const bf16x8*)(&smem[sel][1][br * 32 + (quad ^ (br & 3)) * 8]);
    }
#pragma unroll
    for (int gm = 0; gm < 4; gm++)
#pragma unroll
      for (int gn = 0; gn < 4; gn++)
        acc[gm][gn] =
            __builtin_amdgcn_mfma_f32_16x16x32_bf16(af[gm], bfr[gn], acc[gm][gn], 0, 0, 0);
  }

  const int b = m0 >> 11, l0 = m0 & 2047;
  for (int nhf = 0; nhf < 2; nhf++) {
    int h = (n0 >> 6) + nhf;
    int bh = b * NH_ + h;
    if (ostd) {
      __syncthreads();
      if (wn == nhf) {
#pragma unroll
        for (int gn = 0; gn < 4; gn++) {
          float bi = bias[n0 + nhf * 64 + gn * 16 + lo16];
#pragma unroll
          for (int gm = 0; gm < 4; gm++)
#pragma unroll
            for (int r = 0; r < 4; r++)
              cbuf[(wm * 64 + gm * 16 + quad * 4 + r) * 72 + gn * 16 + lo16] =
                  (__bf16)((acc[gm][gn][r] + bi) * osc);
        }
      }
      __syncthreads();
      int m = t >> 1, coff = (t & 1) * 32;
      __bf16* dst = ostd + ((size_t)bh * LQ_ + l0 + m) * DH_ + coff;
#pragma unroll
      for (int j = 0; j < 4; j++)
        *(bf16x8*)(dst + j * 8) = *(const bf16x8*)&cbuf[m * 72 + coff + j * 8];
    }
    if (otr) {
      __syncthreads();
      if (wn == nhf) {
#pragma unroll
        for (int gn = 0; gn < 4; gn++) {
          float bi = bias[n0 + nhf * 64 + gn * 16 + lo16];
#pragma unroll
          for (int gm = 0; gm < 4; gm++) {
            bf16x4 pk;
#pragma unroll
            for (int r = 0; r < 4; r++) pk[r] = (__bf16)(acc[gm][gn][r] + bi);
            *(bf16x4*)&cbuf[(gn * 16 + lo16) * 136 + wm * 64 + gm * 16 + quad * 4] = pk;
          }
        }
      }
      __syncthreads();
      int d = t >> 2, mc = (t & 3) * 32;
      int kti = (l0 + mc) >> 6, kl = (l0 + mc) & 63;
      __bf16* dst = otr + ((size_t)(bh * NKT_ + kti) * 64 + d) * 64 + kl;
#pragma unroll
      for (int j = 0; j < 4; j++)
        *(bf16x8*)(dst + j * 8) = *(const bf16x8*)&cbuf[d * 136 + mc + j * 8];
    }
  }
}

// Flash attention (R13): twin d/k-split. 8 waves = 4 q-slices (32 rows) x
// 2 twins. Twin t: QK^T for k-half t only (kb reads 4, was 8), publish P^T
// half to the slice's shared p_lds, barrier, then BOTH twins read full-k P
// (4 reads) but compute PV/PK only for d-half t (bv/bk reads 8, was 16).
// ds_read_b128 per wave-tile: 26 -> 16 (LDS read pipe was 84% of elapsed).
// Each (q,d) owned by one wave -> direct stores, NO cross-wave reduction
// (R10's mistake). Staging issued after the mid barrier so both barriers'
// vmcnt drains stay free (stage->consume distance = PV phase; K/V L2-hot:
// all y-blocks of a bh land on XCD bh%8, 3MB < 4MB L2). Swapped QK^T,
// packed b64 P store, lsum via MFMA-ones, setprio on MFMA clusters, Q
// pre-scaled in proj. LDS = 66 KB -> 2 blocks/CU.
__global__ __launch_bounds__(512) void attn_kernel(
    const __bf16* __restrict__ qh, const __bf16* __restrict__ kh,
    const __bf16* __restrict__ khT, const __bf16* __restrict__ vhT,
    const unsigned* __restrict__ maskp,
    float* __restrict__ out_k, float* __restrict__ out_v) {
  __shared__ __align__(16) __bf16 kbuf[2][64 * 64];
  __shared__ __align__(16) __bf16 ktbuf[2][64 * 64];
  __shared__ __align__(16) __bf16 vtbuf[2][64 * 64];
  __shared__ __align__(16) __bf16 p_lds[4][32][72];  // per q-slice P[q][k]

  const int t = threadIdx.x;
  const int wave = t >> 6, lane = t & 63;
  const int lo16 = lane & 15, quad = lane >> 4;
  const int tw = wave & 1;   // twin: k-half for QK, d-half for PV/PK
  const int qs = wave >> 1;  // q-slice (32 rows)
  const int bh = blockIdx.x;
  const int b = bh >> 4, h = bh & 15;
  const int q0 = blockIdx.y * 128 + qs * 32;
  const int srow = lane >> 3;
  const int scg = (lane & 7) ^ srow;  // XOR chunk swizzle (store side)
  const int rsw = lo16 & 7;           // read-side row & 7

  bf16x8 a_q0[2], a_q1[2];  // Q B-frags for the slice's two 16-row blocks
#pragma unroll
  for (int qb = 0; qb < 2; qb++) {
    const __bf16* qrow =
        qh + ((size_t)bh * LQ_ + q0 + qb * 16 + lo16) * DH_ + quad * 8;
    a_q0[qb] = *(const bf16x8*)(qrow);
    a_q1[qb] = *(const bf16x8*)(qrow + 32);
  }

  bf16x8 ones;
#pragma unroll
  for (int j = 0; j < 8; j++) ones[j] = (__bf16)1.0f;

  f32x4 acc_v[2][2] = {};  // [qb][gg(d16-block within twin's d-half)]
  f32x4 acc_k[2][2] = {};
  f32x4 acc_l[2] = {};

  const __bf16* khb = kh + (size_t)bh * LK_ * DH_;
  const __bf16* ktb = khT + (size_t)bh * LK_ * DH_;
  const __bf16* vtb = vhT + (size_t)bh * LK_ * DH_;

  const int row_s = wave * 8 + srow;
  auto stage = [&](int kti, int sel) {
    const int tb = kti * 4096;
    gload_lds16(khb + (size_t)(kti * 64 + row_s) * DH_ + scg * 8, &kbuf[sel][wave * 512]);
    gload_lds16(ktb + tb + row_s * 64 + scg * 8, &ktbuf[sel][wave * 512]);
    gload_lds16(vtb + tb + row_s * 64 + scg * 8, &vtbuf[sel][wave * 512]);
  };

  stage(0, 0);
  for (int kti = 0; kti < NKT_; kti++) {
    const int cur = kti & 1;
    __syncthreads();  // drains stage(cur), issued a full PV-phase ago

    // this lane's q-row mask words for twin's k-half (early issue)
    unsigned mw[2];
#pragma unroll
    for (int qb = 0; qb < 2; qb++)
      mw[qb] = maskp[((size_t)b * LQ_ + q0 + qb * 16 + lo16) * (LK_ / 32) +
                     kti * 2 + tw];

    // ---- S^T = K Q^T over twin's k-half ----
    __builtin_amdgcn_s_setprio(1);
    f32x4 s[2][2];  // [qb][gg(k16-block within half)]
#pragma unroll
    for (int gg = 0; gg < 2; gg++) {
      int krow = tw * 32 + gg * 16 + lo16;
      bf16x8 kb0 = *(const bf16x8*)(&kbuf[cur][krow * 64 + ((quad ^ rsw) * 8)]);
      bf16x8 kb1 = *(const bf16x8*)(&kbuf[cur][krow * 64 + (((quad + 4) ^ rsw) * 8)]);
#pragma unroll
      for (int qb = 0; qb < 2; qb++) {
        f32x4 z = {};
        z = __builtin_amdgcn_mfma_f32_16x16x32_bf16(kb0, a_q0[qb], z, 0, 0, 0);
        z = __builtin_amdgcn_mfma_f32_16x16x32_bf16(kb1, a_q1[qb], z, 0, 0, 0);
        s[qb][gg] = z;  // row k_loc = gg*16+quad*4+r (in half), col q = lo16
      }
    }
    __builtin_amdgcn_s_setprio(0);

    // ---- mask + exp2 + packed P^half store ----
#pragma unroll
    for (int qb = 0; qb < 2; qb++)
#pragma unroll
      for (int gg = 0; gg < 2; gg++) {
        bf16x4 pk;
#pragma unroll
        for (int r = 0; r < 4; r++) {
          int bitpos = gg * 16 + quad * 4 + r;
          float pe = __builtin_amdgcn_exp2f(s[qb][gg][r]);
          pk[r] = ((mw[qb] >> bitpos) & 1) ? (__bf16)pe : (__bf16)0.0f;
        }
        *(bf16x4*)&p_lds[qs][qb * 16 + lo16][tw * 32 + gg * 16 + quad * 4] = pk;
      }

    __syncthreads();  // cross-twin: both P halves visible

    // ---- full-k P A-frags ----
    bf16x8 a_p[2][2];  // [qb][kh]
#pragma unroll
    for (int qb = 0; qb < 2; qb++)
#pragma unroll
      for (int kh = 0; kh < 2; kh++)
        a_p[qb][kh] =
            *(const bf16x8*)&p_lds[qs][qb * 16 + lo16][kh * 32 + quad * 8];

    // prefetch next tile AFTER the mid barrier (drained at next top barrier)
    if (kti + 1 < NKT_) stage(kti + 1, cur ^ 1);

    // ---- O_v += P V, O_k += P K over twin's d-half; lsum += P 1 ----
    __builtin_amdgcn_s_setprio(1);
#pragma unroll
    for (int gg = 0; gg < 2; gg++) {
      int rowd = tw * 32 + gg * 16 + lo16;
      bf16x8 bv[2], bk[2];
#pragma unroll
      for (int kh = 0; kh < 2; kh++) {
        int ch = ((quad + kh * 4) ^ rsw) * 8;
        bv[kh] = *(const bf16x8*)(&vtbuf[cur][rowd * 64 + ch]);
        bk[kh] = *(const bf16x8*)(&ktbuf[cur][rowd * 64 + ch]);
      }
#pragma unroll
      for (int qb = 0; qb < 2; qb++)
#pragma unroll
        for (int kh = 0; kh < 2; kh++) {
          acc_v[qb][gg] = __builtin_amdgcn_mfma_f32_16x16x32_bf16(
              a_p[qb][kh], bv[kh], acc_v[qb][gg], 0, 0, 0);
          acc_k[qb][gg] = __builtin_amdgcn_mfma_f32_16x16x32_bf16(
              a_p[qb][kh], bk[kh], acc_k[qb][gg], 0, 0, 0);
        }
    }
#pragma unroll
    for (int qb = 0; qb < 2; qb++)
#pragma unroll
      for (int kh = 0; kh < 2; kh++)
        acc_l[qb] = __builtin_amdgcn_mfma_f32_16x16x32_bf16(
            a_p[qb][kh], ones, acc_l[qb], 0, 0, 0);
    __builtin_amdgcn_s_setprio(0);
  }

  // each wave owns (32 q) x (its d-half) of both outputs -> direct stores
#pragma unroll
  for (int qb = 0; qb < 2; qb++) {
    float inv_l[4];
#pragma unroll
    for (int r = 0; r < 4; r++) inv_l[r] = 1.0f / acc_l[qb][r];
    size_t obase =
        ((size_t)b * LQ_ + q0 + qb * 16 + quad * 4) * DM_ + h * DH_ + tw * 32;
#pragma unroll
    for (int gg = 0; gg < 2; gg++) {
#pragma unroll
      for (int r = 0; r < 4; r++) {
        size_t idx = obase + (size_t)r * DM_ + gg * 16 + lo16;
        out_k[idx] = acc_k[qb][gg][r] * inv_l[r];
        out_v[idx] = acc_v[qb][gg][r] * inv_l[r];
      }
    }
  }
}

extern "C" void kernel_launch(void* const* d_in, const int* in_sizes, int n_in,
                              void* d_out, int out_size, void* d_ws, size_t ws_size,
                              hipStream_t stream) {
  const float* q = (const float*)d_in[0];
  const float* k = (const float*)d_in[1];
  const float* v = (const float*)d_in[2];
  const int* mask = (const int*)d_in[3];
  const float* Wq = (const float*)d_in[4];
  const float* bq = (const float*)d_in[5];
  const float* Wk = (const float*)d_in[6];
  const float* bk = (const float*)d_in[7];
  const float* Wv = (const float*)d_in[8];
  const float* bv = (const float*)d_in[9];
  float* out = (float*)d_out;

  // ws: qh | kh | khT | vhT (bf16, 8.4MB ea) | maskp (1MB) | [scratch if fits]
  const size_t HTOT = (size_t)B_ * NH_ * LQ_ * DH_;
  const size_t XTOT = (size_t)B_ * LQ_ * DM_;
  const size_t MASKW = (size_t)B_ * LQ_ * (LK_ / 32);
  __bf16* qh = (__bf16*)d_ws;
  __bf16* kh = qh + HTOT;
  __bf16* khT = kh + HTOT;
  __bf16* vhT = khT + HTOT;
  unsigned* maskp = (unsigned*)(vhT + HTOT);

  // k-tiled bf16 X/W scratch (31.5 MB): prefer tail of d_ws; fall back to
  // d_out (dead until attn writes outputs) when ws is too small.
  const size_t SCR_ELEMS = 3 * XTOT + 3 * (size_t)DM_ * DM_;
  const size_t NEED = 4 * HTOT * sizeof(__bf16) + MASKW * sizeof(unsigned) +
                      SCR_ELEMS * sizeof(__bf16);
  __bf16* scr = (ws_size >= NEED) ? (__bf16*)(maskp + MASKW) : (__bf16*)d_out;
  __bf16* Xt0 = scr;
  __bf16* Xt1 = Xt0 + XTOT;
  __bf16* Xt2 = Xt1 + XTOT;
  __bf16* Wt0 = Xt2 + XTOT;
  __bf16* Wt1 = Wt0 + (size_t)DM_ * DM_;
  __bf16* Wt2 = Wt1 + (size_t)DM_ * DM_;

  prep_kernel<<<960 + 8192, 256, 0, stream>>>(
      q, k, v, Wq, Wk, Wv, mask, Xt0, Xt1, Xt2, Wt0, Wt1, Wt2, maskp);
  proj_kernel<<<dim3(32, 8, 3), 256, 0, stream>>>(
      Xt0, Xt1, Xt2, bq, bk, bv, Wt0, Wt1, Wt2, qh, kh, khT, vhT);
  attn_kernel<<<dim3(32, 16), 512, 0, stream>>>(qh, kh, khT, vhT, maskp,
                                                out, out + (size_t)B_ * LQ_ * DM_);
}

// Round 9
// 252.616 us; speedup vs baseline: 1.1477x; 1.1477x over previous
//
#include <hip/hip_runtime.h>
#include <hip/hip_bf16.h>
#include <stdint.h>

typedef __bf16 bf16x8 __attribute__((ext_vector_type(8)));
typedef __bf16 bf16x4 __attribute__((ext_vector_type(4)));
typedef float f32x4 __attribute__((ext_vector_type(4)));

#define B_ 2
#define LQ_ 2048
#define LK_ 2048
#define NH_ 16
#define DH_ 64
#define DM_ 1024
#define NKT_ (LK_ / 64)

#define AS1 __attribute__((address_space(1)))
#define AS3 __attribute__((address_space(3)))

__device__ __forceinline__ void gload_lds16(const void* g, void* l) {
  __builtin_amdgcn_global_load_lds((const AS1 uint32_t*)g, (AS3 uint32_t*)l, 16, 0, 0);
}

// Fused prep: blocks [0,960) convert q,k,v,Wq,Wk,Wv fp32 -> bf16 k-tiled
// T[kt][row][32] (chunk c' stores true chunk c'^(row&3)); blocks [960,9152)
// pack the mask to bits.
__global__ __launch_bounds__(256) void prep_kernel(
    const float* __restrict__ q, const float* __restrict__ k,
    const float* __restrict__ v, const float* __restrict__ wq,
    const float* __restrict__ wk, const float* __restrict__ wv,
    const int* __restrict__ mask,
    __bf16* __restrict__ Xt0, __bf16* __restrict__ Xt1, __bf16* __restrict__ Xt2,
    __bf16* __restrict__ Wt0, __bf16* __restrict__ Wt1, __bf16* __restrict__ Wt2,
    unsigned* __restrict__ maskp) {
  const int t = threadIdx.x;
  const int bidx = blockIdx.x;
  if (bidx >= 960) {
    // ---- mask pack: thread covers 4 ints; nibble OR-reduce over 8 lanes ----
    int pb = bidx - 960;
    int lane = t & 63;
    size_t gi = ((size_t)pb * 256 + t) * 4;
    int4 mv = *(const int4*)(mask + gi);
    unsigned nib = (mv.x != 0 ? 1u : 0u) | (mv.y != 0 ? 2u : 0u) |
                   (mv.z != 0 ? 4u : 0u) | (mv.w != 0 ? 8u : 0u);
    unsigned vv = nib << ((lane & 7) * 4);
    vv |= __shfl_xor(vv, 1, 64);
    vv |= __shfl_xor(vv, 2, 64);
    vv |= __shfl_xor(vv, 4, 64);
    if ((lane & 7) == 0) maskp[gi >> 5] = vv;
    return;
  }
  // ---- cvt: 16 source rows x 1024 k through LDS transpose ----
  __shared__ __align__(16) __bf16 lb[16][1032];
  const float* src; __bf16* dst; int rows, m0;
  if (bidx < 256)      { src = q;  dst = Xt0; rows = 4096; m0 = bidx * 16; }
  else if (bidx < 512) { src = k;  dst = Xt1; rows = 4096; m0 = (bidx - 256) * 16; }
  else if (bidx < 768) { src = v;  dst = Xt2; rows = 4096; m0 = (bidx - 512) * 16; }
  else if (bidx < 832) { src = wq; dst = Wt0; rows = 1024; m0 = (bidx - 768) * 16; }
  else if (bidx < 896) { src = wk; dst = Wt1; rows = 1024; m0 = (bidx - 832) * 16; }
  else                 { src = wv; dst = Wt2; rows = 1024; m0 = (bidx - 896) * 16; }
#pragma unroll
  for (int i = 0; i < 16; i++) {
    float4 f = *(const float4*)(src + (size_t)(m0 + i) * DM_ + t * 4);
    bf16x4 o;
    o[0] = (__bf16)f.x; o[1] = (__bf16)f.y; o[2] = (__bf16)f.z; o[3] = (__bf16)f.w;
    *(bf16x4*)&lb[i][t * 4] = o;
  }
  __syncthreads();
  const int wave = t >> 6, lane = t & 63;
  const int m = lane >> 2, c = lane & 3;
#pragma unroll
  for (int j = 0; j < 8; j++) {
    int kt = wave * 8 + j;
    bf16x8 val = *(const bf16x8*)&lb[m][kt * 32 + (c ^ (m & 3)) * 8];
    *(bf16x8*)(dst + ((size_t)kt * rows + m0 + m) * 32 + c * 8) = val;  // 1KB/instr
  }
}

// GEMM C = X @ W^T + bias, 128x128 tile, BK=32, double-buffered staging from
// k-tiled inputs: each global_load_lds covers one contiguous 1KB span.
// mode=blockIdx.z: 0=q(std), 1=k(std+T), 2=v(T). T out: T[bh][kti][d][64].
// mode-0 (qh) output pre-scaled by log2e/8 so attn's exp2 needs no mul.
__global__ __launch_bounds__(256) void proj_kernel(
    const __bf16* __restrict__ Xt0, const __bf16* __restrict__ Xt1,
    const __bf16* __restrict__ Xt2,
    const float* __restrict__ b0p, const float* __restrict__ b1p,
    const float* __restrict__ b2p,
    const __bf16* __restrict__ Wt0, const __bf16* __restrict__ Wt1,
    const __bf16* __restrict__ Wt2,
    __bf16* __restrict__ qh, __bf16* __restrict__ kh,
    __bf16* __restrict__ khT, __bf16* __restrict__ vhT) {
  __shared__ __align__(16) __bf16 smem[2][2][128 * 32];
  __bf16* cbuf = &smem[0][0][0];  // epilogue alias (18 KB < 32 KB)

  const int mode = blockIdx.z;
  const __bf16* Xt = mode == 0 ? Xt0 : (mode == 1 ? Xt1 : Xt2);
  const __bf16* Wt = mode == 0 ? Wt0 : (mode == 1 ? Wt1 : Wt2);
  const float* bias = mode == 0 ? b0p : (mode == 1 ? b1p : b2p);
  __bf16* ostd = mode == 0 ? qh : (mode == 1 ? kh : nullptr);
  __bf16* otr = mode == 0 ? nullptr : (mode == 1 ? khT : vhT);
  const float osc = mode == 0 ? 0.18033688f : 1.0f;  // log2(e)/8 folded into Q

  const int t = threadIdx.x;
  const int wave = t >> 6, lane = t & 63;
  const int lo16 = lane & 15, quad = lane >> 4;
  const int wm = wave >> 1, wn = wave & 1;
  const int m0 = blockIdx.x * 128, n0 = blockIdx.y * 128;

  f32x4 acc[4][4] = {};

  auto stage = [&](int kt, int sel) {
#pragma unroll
    for (int ii = 2 * wave; ii < 2 * wave + 2; ii++) {
      gload_lds16(Xt + ((size_t)kt * 4096 + m0 + ii * 16) * 32 + lane * 8,
                  &smem[sel][0][ii * 512]);
      gload_lds16(Wt + ((size_t)kt * 1024 + n0 + ii * 16) * 32 + lane * 8,
                  &smem[sel][1][ii * 512]);
    }
  };

  stage(0, 0);
  for (int kt = 0; kt < 32; kt++) {
    const int sel = kt & 1;
    __syncthreads();
    if (kt + 1 < 32) stage(kt + 1, sel ^ 1);
    bf16x8 af[4], bfr[4];
#pragma unroll
    for (int g = 0; g < 4; g++) {
      int ar = wm * 64 + g * 16 + lo16;
      af[g] = *(const bf16x8*)(&smem[sel][0][ar * 32 + (quad ^ (ar & 3)) * 8]);
      int br = wn * 64 + g * 16 + lo16;
      bfr[g] = *(const bf16x8*)(&smem[sel][1][br * 32 + (quad ^ (br & 3)) * 8]);
    }
#pragma unroll
    for (int gm = 0; gm < 4; gm++)
#pragma unroll
      for (int gn = 0; gn < 4; gn++)
        acc[gm][gn] =
            __builtin_amdgcn_mfma_f32_16x16x32_bf16(af[gm], bfr[gn], acc[gm][gn], 0, 0, 0);
  }

  const int b = m0 >> 11, l0 = m0 & 2047;
  for (int nhf = 0; nhf < 2; nhf++) {
    int h = (n0 >> 6) + nhf;
    int bh = b * NH_ + h;
    if (ostd) {
      __syncthreads();
      if (wn == nhf) {
#pragma unroll
        for (int gn = 0; gn < 4; gn++) {
          float bi = bias[n0 + nhf * 64 + gn * 16 + lo16];
#pragma unroll
          for (int gm = 0; gm < 4; gm++)
#pragma unroll
            for (int r = 0; r < 4; r++)
              cbuf[(wm * 64 + gm * 16 + quad * 4 + r) * 72 + gn * 16 + lo16] =
                  (__bf16)((acc[gm][gn][r] + bi) * osc);
        }
      }
      __syncthreads();
      int m = t >> 1, coff = (t & 1) * 32;
      __bf16* dst = ostd + ((size_t)bh * LQ_ + l0 + m) * DH_ + coff;
#pragma unroll
      for (int j = 0; j < 4; j++)
        *(bf16x8*)(dst + j * 8) = *(const bf16x8*)&cbuf[m * 72 + coff + j * 8];
    }
    if (otr) {
      __syncthreads();
      if (wn == nhf) {
#pragma unroll
        for (int gn = 0; gn < 4; gn++) {
          float bi = bias[n0 + nhf * 64 + gn * 16 + lo16];
#pragma unroll
          for (int gm = 0; gm < 4; gm++) {
            bf16x4 pk;
#pragma unroll
            for (int r = 0; r < 4; r++) pk[r] = (__bf16)(acc[gm][gn][r] + bi);
            *(bf16x4*)&cbuf[(gn * 16 + lo16) * 136 + wm * 64 + gm * 16 + quad * 4] = pk;
          }
        }
      }
      __syncthreads();
      int d = t >> 2, mc = (t & 3) * 32;
      int kti = (l0 + mc) >> 6, kl = (l0 + mc) & 63;
      __bf16* dst = otr + ((size_t)(bh * NKT_ + kti) * 64 + d) * 64 + kl;
#pragma unroll
      for (int j = 0; j < 4; j++)
        *(bf16x8*)(dst + j * 8) = *(const bf16x8*)&cbuf[d * 136 + mc + j * 8];
    }
  }
}

// Flash attention (R14 = R12, verified 79.4us, + mask-word software pipeline).
// R12 structure: 8 waves x 16 q-rows (512 thr), 2 blocks/CU; swapped QK^T
// (mfma(K,Q) -> lane-local q-row, packed b64 P store, 2 mask words/lane);
// scalar-free lsum via MFMA-with-ones; Q pre-scaled in proj -> bare exp2;
// setprio around MFMA clusters. R14 change: mask words for tile t+1 are
// loaded during tile t's compute (global-load latency ~200-900cy was hitting
// the critical chain ~50cy after issue). +2 VGPR, no new barriers.
// (R10/R13 lesson: cross-wave work-splits with a per-tile barrier regress
// ~15-40% from barrier serialization — do not revisit.)
__global__ __launch_bounds__(512) void attn_kernel(
    const __bf16* __restrict__ qh, const __bf16* __restrict__ kh,
    const __bf16* __restrict__ khT, const __bf16* __restrict__ vhT,
    const unsigned* __restrict__ maskp,
    float* __restrict__ out_k, float* __restrict__ out_v) {
  __shared__ __align__(16) __bf16 kbuf[2][64 * 64];
  __shared__ __align__(16) __bf16 ktbuf[2][64 * 64];
  __shared__ __align__(16) __bf16 vtbuf[2][64 * 64];
  __shared__ __align__(16) __bf16 p_lds[8][16][72];  // per-wave P[q][k]

  const int t = threadIdx.x;
  const int wave = t >> 6, lane = t & 63;
  const int lo16 = lane & 15, quad = lane >> 4;
  const int bh = blockIdx.x;
  const int b = bh >> 4, h = bh & 15;
  const int q0 = blockIdx.y * 128 + wave * 16;
  const int srow = lane >> 3;
  const int scg = (lane & 7) ^ srow;  // XOR chunk swizzle (store side)
  const int rsw = lo16 & 7;           // read-side row & 7

  bf16x8 a_q0, a_q1;
  {
    const __bf16* qrow = qh + ((size_t)bh * LQ_ + q0 + lo16) * DH_ + quad * 8;
    a_q0 = *(const bf16x8*)(qrow);
    a_q1 = *(const bf16x8*)(qrow + 32);
  }

  bf16x8 ones;
#pragma unroll
  for (int j = 0; j < 8; j++) ones[j] = (__bf16)1.0f;

  f32x4 acc_v[4] = {};
  f32x4 acc_k[4] = {};
  f32x4 acc_l = {};

  const __bf16* khb = kh + (size_t)bh * LK_ * DH_;
  const __bf16* ktb = khT + (size_t)bh * LK_ * DH_;
  const __bf16* vtb = vhT + (size_t)bh * LK_ * DH_;

  const int row_s = wave * 8 + srow;
  auto stage = [&](int kti, int sel) {
    const int tb = kti * 4096;
    gload_lds16(khb + (size_t)(kti * 64 + row_s) * DH_ + scg * 8, &kbuf[sel][wave * 512]);
    gload_lds16(ktb + tb + row_s * 64 + scg * 8, &ktbuf[sel][wave * 512]);
    gload_lds16(vtb + tb + row_s * 64 + scg * 8, &vtbuf[sel][wave * 512]);
  };

  // this lane's q-row mask stream; tile-0 words loaded before the loop
  const unsigned* mrow = maskp + ((size_t)b * LQ_ + q0 + lo16) * (LK_ / 32);
  unsigned mw0 = mrow[0], mw1 = mrow[1];

  stage(0, 0);
  for (int kti = 0; kti < NKT_; kti++) {
    const int cur = kti & 1;
    __syncthreads();  // drains stage(cur), issued a full compute-phase ago
    if (kti + 1 < NKT_) stage(kti + 1, cur ^ 1);

    // prefetch next tile's mask words (consumed next iteration -> full
    // compute-phase of latency hiding)
    unsigned nm0 = 0, nm1 = 0;
    if (kti + 1 < NKT_) {
      nm0 = mrow[(kti + 1) * 2];
      nm1 = mrow[(kti + 1) * 2 + 1];
    }

    // ---- S^T = K Q^T (swapped operands; same registers, same reads) ----
    __builtin_amdgcn_s_setprio(1);
    f32x4 s[4];
#pragma unroll
    for (int gg = 0; gg < 4; gg++) {
      int row = gg * 16 + lo16;
      bf16x8 kb0 = *(const bf16x8*)(&kbuf[cur][row * 64 + ((quad ^ rsw) * 8)]);
      bf16x8 kb1 = *(const bf16x8*)(&kbuf[cur][row * 64 + (((quad + 4) ^ rsw) * 8)]);
      f32x4 z = {};
      z = __builtin_amdgcn_mfma_f32_16x16x32_bf16(kb0, a_q0, z, 0, 0, 0);
      z = __builtin_amdgcn_mfma_f32_16x16x32_bf16(kb1, a_q1, z, 0, 0, 0);
      s[gg] = z;  // C[row=k_local=quad*4+r][col=q=lo16]; k = gg*16+quad*4+r
    }
    __builtin_amdgcn_s_setprio(0);

    // ---- mask + exp2 (Q pre-scaled; fixed max) + packed P store ----
#pragma unroll
    for (int gg = 0; gg < 4; gg++) {
      unsigned w = (gg >= 2) ? mw1 : mw0;
      bf16x4 pk;
#pragma unroll
      for (int r = 0; r < 4; r++) {
        int bitpos = (gg & 1) * 16 + quad * 4 + r;
        float pe = __builtin_amdgcn_exp2f(s[gg][r]);
        pk[r] = ((w >> bitpos) & 1) ? (__bf16)pe : (__bf16)0.0f;
      }
      *(bf16x4*)&p_lds[wave][lo16][gg * 16 + quad * 4] = pk;  // k-contiguous
    }
    bf16x8 a_p0 = *(const bf16x8*)&p_lds[wave][lo16][quad * 8];
    bf16x8 a_p1 = *(const bf16x8*)&p_lds[wave][lo16][32 + quad * 8];

    // ---- O_v += P V, O_k += P K, lsum += P 1 ----
    __builtin_amdgcn_s_setprio(1);
#pragma unroll
    for (int gg = 0; gg < 4; gg++) {
      int row = gg * 16 + lo16;
      bf16x8 bv0 = *(const bf16x8*)(&vtbuf[cur][row * 64 + ((quad ^ rsw) * 8)]);
      bf16x8 bv1 = *(const bf16x8*)(&vtbuf[cur][row * 64 + (((quad + 4) ^ rsw) * 8)]);
      bf16x8 bk0 = *(const bf16x8*)(&ktbuf[cur][row * 64 + ((quad ^ rsw) * 8)]);
      bf16x8 bk1 = *(const bf16x8*)(&ktbuf[cur][row * 64 + (((quad + 4) ^ rsw) * 8)]);
      acc_v[gg] = __builtin_amdgcn_mfma_f32_16x16x32_bf16(a_p0, bv0, acc_v[gg], 0, 0, 0);
      acc_v[gg] = __builtin_amdgcn_mfma_f32_16x16x32_bf16(a_p1, bv1, acc_v[gg], 0, 0, 0);
      acc_k[gg] = __builtin_amdgcn_mfma_f32_16x16x32_bf16(a_p0, bk0, acc_k[gg], 0, 0, 0);
      acc_k[gg] = __builtin_amdgcn_mfma_f32_16x16x32_bf16(a_p1, bk1, acc_k[gg], 0, 0, 0);
    }
    acc_l = __builtin_amdgcn_mfma_f32_16x16x32_bf16(a_p0, ones, acc_l, 0, 0, 0);
    acc_l = __builtin_amdgcn_mfma_f32_16x16x32_bf16(a_p1, ones, acc_l, 0, 0, 0);
    __builtin_amdgcn_s_setprio(0);

    mw0 = nm0;
    mw1 = nm1;
  }

  // acc_l: every column equals the row-sum -> per-reg reciprocal, no shuffle
  float inv_l[4];
#pragma unroll
  for (int r = 0; r < 4; r++) inv_l[r] = 1.0f / acc_l[r];
  size_t obase = ((size_t)b * LQ_ + q0 + quad * 4) * DM_ + h * DH_;
#pragma unroll
  for (int gg = 0; gg < 4; gg++) {
#pragma unroll
    for (int r = 0; r < 4; r++) {
      size_t idx = obase + (size_t)r * DM_ + gg * 16 + lo16;
      out_k[idx] = acc_k[gg][r] * inv_l[r];
      out_v[idx] = acc_v[gg][r] * inv_l[r];
    }
  }
}

extern "C" void kernel_launch(void* const* d_in, const int* in_sizes, int n_in,
                              void* d_out, int out_size, void* d_ws, size_t ws_size,
                              hipStream_t stream) {
  const float* q = (const float*)d_in[0];
  const float* k = (const float*)d_in[1];
  const float* v = (const float*)d_in[2];
  const int* mask = (const int*)d_in[3];
  const float* Wq = (const float*)d_in[4];
  const float* bq = (const float*)d_in[5];
  const float* Wk = (const float*)d_in[6];
  const float* bk = (const float*)d_in[7];
  const float* Wv = (const float*)d_in[8];
  const float* bv = (const float*)d_in[9];
  float* out = (float*)d_out;

  // ws: qh | kh | khT | vhT (bf16, 8.4MB ea) | maskp (1MB) | [scratch if fits]
  const size_t HTOT = (size_t)B_ * NH_ * LQ_ * DH_;
  const size_t XTOT = (size_t)B_ * LQ_ * DM_;
  const size_t MASKW = (size_t)B_ * LQ_ * (LK_ / 32);
  __bf16* qh = (__bf16*)d_ws;
  __bf16* kh = qh + HTOT;
  __bf16* khT = kh + HTOT;
  __bf16* vhT = khT + HTOT;
  unsigned* maskp = (unsigned*)(vhT + HTOT);

  // k-tiled bf16 X/W scratch (31.5 MB): prefer tail of d_ws; fall back to
  // d_out (dead until attn writes outputs) when ws is too small.
  const size_t SCR_ELEMS = 3 * XTOT + 3 * (size_t)DM_ * DM_;
  const size_t NEED = 4 * HTOT * sizeof(__bf16) + MASKW * sizeof(unsigned) +
                      SCR_ELEMS * sizeof(__bf16);
  __bf16* scr = (ws_size >= NEED) ? (__bf16*)(maskp + MASKW) : (__bf16*)d_out;
  __bf16* Xt0 = scr;
  __bf16* Xt1 = Xt0 + XTOT;
  __bf16* Xt2 = Xt1 + XTOT;
  __bf16* Wt0 = Xt2 + XTOT;
  __bf16* Wt1 = Wt0 + (size_t)DM_ * DM_;
  __bf16* Wt2 = Wt1 + (size_t)DM_ * DM_;

  prep_kernel<<<960 + 8192, 256, 0, stream>>>(
      q, k, v, Wq, Wk, Wv, mask, Xt0, Xt1, Xt2, Wt0, Wt1, Wt2, maskp);
  proj_kernel<<<dim3(32, 8, 3), 256, 0, stream>>>(
      Xt0, Xt1, Xt2, bq, bk, bv, Wt0, Wt1, Wt2, qh, kh, khT, vhT);
  attn_kernel<<<dim3(32, 16), 512, 0, stream>>>(qh, kh, khT, vhT, maskp,
                                                out, out + (size_t)B_ * LQ_ * DM_);
}